// Round 4
// baseline (134.279 us; speedup 1.0000x reference)
//
#include <hip/hip_runtime.h>
#include <stdint.h>

#define C_DIM   256
#define L_ANCH  8
#define M_INST  64
#define NPIX    32768
#define LDSTR   264      // LDS tile row stride (shorts)
#define GUSTR   512      // interleaved G|U row stride (shorts)

typedef __attribute__((ext_vector_type(8))) short  short8;   // 8 x bf16
typedef __attribute__((ext_vector_type(4))) float  float4v;  // MFMA C/D

__device__ __forceinline__ float bf2f(unsigned short b) {
    union { unsigned u; float f; } x; x.u = ((unsigned)b) << 16; return x.f;
}
__device__ __forceinline__ unsigned short f2bf(float f) {
    union { unsigned u; float f; } x; x.f = f;
    unsigned u = x.u;
    return (unsigned short)((u + 0x7FFFu + ((u >> 16) & 1u)) >> 16);  // RNE
}
__device__ __forceinline__ ushort4 f4bf(float4 f) {
    ushort4 v; v.x = f2bf(f.x); v.y = f2bf(f.y); v.z = f2bf(f.z); v.w = f2bf(f.w);
    return v;
}
__device__ __forceinline__ short8 f8bf(float4 a, float4 b) {
    union { short8 v; ushort4 q[2]; } u;
    u.q[0] = f4bf(a); u.q[1] = f4bf(b);
    return u.v;
}
// unpack 2 bf16 packed in a dword: 1 VALU op per element
__device__ __forceinline__ void bfx2(unsigned u, float& lo, float& hi) {
    union { unsigned u; float f; } a, b;
    a.u = u << 16; b.u = u & 0xffff0000u;
    lo = a.f; hi = b.f;
}

// ---------------------------------------------------------------------------
// FUSED prep: 64 blocks.  b<32 => G path, else U path; tile=(b>>1)&15 (32
// anchor rows), half=b&1 (128 output cols of GEMM2).
//   phase A: stage A-tile (anchors, fp32->bf16) into Abuf
//   GEMM1  : T = A @ W1^T + b1  (W1 = Wk or Wv) -> Tbuf in LDS (full 256
//            cols per block; duplicated across the two halves — trivial work,
//            removes the Kb/Vb global round-trip and one kernel launch)
//   g0     : (G path, half 0) g0 = T . bq from Tbuf
//   GEMM2  : GU = T @ W2      (W2 = Wq columns via coalesced scalar loads,
//            or out_w rows via float4) -> interleaved GU buffer
// All weight traffic is L2-resident; the chain is latency-bound, so fusing
// the two GEMMs back-to-back in LDS beats two launches + global round-trip.
// ---------------------------------------------------------------------------
__global__ __launch_bounds__(256) void prep_kernel(
    const float* __restrict__ anchors, const float* __restrict__ in_proj_w,
    const float* __restrict__ in_proj_b, const float* __restrict__ out_w,
    unsigned short* __restrict__ GU, float* __restrict__ g0)
{
    __shared__ unsigned short Abuf[32 * LDSTR];
    __shared__ unsigned short Tbuf[32 * LDSTR];
    const int b = blockIdx.x, t = threadIdx.x;
    const int isG = (b < 32) ? 1 : 0;
    const int tile = (b >> 1) & 15, half = b & 1;
    const int m0 = tile * 32;
    const int ucol = isG ? 0 : 256;

    // ---- phase A: stage anchor tile (32 x 256 fp32 -> bf16 LDS) ----
#pragma unroll
    for (int i = 0; i < 8; ++i) {
        int id = t + i * 256;
        int row = id >> 6, c4 = id & 63;
        float4 f = *((const float4*)(anchors + (size_t)(m0 + row) * C_DIM) + c4);
        *(ushort4*)&Abuf[row * LDSTR + c4 * 4] = f4bf(f);
    }
    __syncthreads();

    const int wave = t >> 6, lane = t & 63, r16 = lane & 15, quad = lane >> 4;

    // ---- GEMM1: T[l,d] = sum_c A[l,c] * W1[d,c] + b1[d] ----
    const int w1base = C_DIM + (isG ? 0 : C_DIM);   // Wk rows 256.., Wv rows 512..
    const int cb1 = wave * 64;                      // 64 cols per wave

    float4v acc1[2][4];
#pragma unroll
    for (int mt = 0; mt < 2; ++mt)
#pragma unroll
        for (int nt = 0; nt < 4; ++nt)
#pragma unroll
            for (int r = 0; r < 4; ++r) acc1[mt][nt][r] = 0.f;

#pragma unroll 2
    for (int ks = 0; ks < 8; ++ks) {
        const int c0 = ks * 32 + quad * 8;
        short8 afr[2], bfr[4];
#pragma unroll
        for (int mt = 0; mt < 2; ++mt)
            afr[mt] = *(const short8*)&Abuf[(mt * 16 + r16) * LDSTR + c0];
#pragma unroll
        for (int nt = 0; nt < 4; ++nt) {
            const float* wrow = in_proj_w + (size_t)(w1base + cb1 + nt * 16 + r16) * C_DIM + c0;
            bfr[nt] = f8bf(*(const float4*)wrow, *(const float4*)(wrow + 4));
        }
#pragma unroll
        for (int mt = 0; mt < 2; ++mt)
#pragma unroll
            for (int nt = 0; nt < 4; ++nt)
                acc1[mt][nt] = __builtin_amdgcn_mfma_f32_16x16x32_bf16(
                    afr[mt], bfr[nt], acc1[mt][nt], 0, 0, 0);
    }

    // epilogue: T -> Tbuf (bf16, bias added — matches old Kb/Vb rounding)
#pragma unroll
    for (int nt = 0; nt < 4; ++nt) {
        const int col = cb1 + nt * 16 + r16;
        const float bias = in_proj_b[w1base + col];
#pragma unroll
        for (int mt = 0; mt < 2; ++mt)
#pragma unroll
            for (int r = 0; r < 4; ++r) {
                int row = mt * 16 + quad * 4 + r;
                Tbuf[row * LDSTR + col] = f2bf(acc1[mt][nt][r] + bias);
            }
    }
    __syncthreads();

    // ---- g0 = T . bq (G path, half 0 only; block-uniform branch) ----
    if (isG && half == 0) {
        const int grow = t >> 3, gs = t & 7;
        const unsigned short* tr = &Tbuf[grow * LDSTR + gs * 32];
        const float* bp = in_proj_b + gs * 32;
        float gp = 0.f;
#pragma unroll
        for (int c = 0; c < 32; ++c)
            gp += bf2f(tr[c]) * bp[c];
        gp += __shfl_down(gp, 1);
        gp += __shfl_down(gp, 2);
        gp += __shfl_down(gp, 4);
        if (gs == 0) g0[m0 + grow] = gp;
    }

    // ---- GEMM2: GU[l, col] = sum_d T[l,d] * W2[col, d] ----
    const int cb2 = half * 128 + wave * 32;

    float4v acc2[2][2];
#pragma unroll
    for (int mt = 0; mt < 2; ++mt)
#pragma unroll
        for (int nt = 0; nt < 2; ++nt)
#pragma unroll
            for (int r = 0; r < 4; ++r) acc2[mt][nt][r] = 0.f;

#pragma unroll 2
    for (int ks = 0; ks < 8; ++ks) {
        const int c0 = ks * 32 + quad * 8;
        short8 afr[2], bfr[2];
#pragma unroll
        for (int mt = 0; mt < 2; ++mt)
            afr[mt] = *(const short8*)&Tbuf[(mt * 16 + r16) * LDSTR + c0];
#pragma unroll
        for (int nt = 0; nt < 2; ++nt) {
            const int col = cb2 + nt * 16 + r16;
            if (isG) {
                // B row n=col needs Wq[:,col]: 8 scalar fp32 loads, stride
                // C_DIM — coalesced across the 16 r16-lanes (consecutive cols)
                unsigned short tmp[8];
#pragma unroll
                for (int j = 0; j < 8; ++j)
                    tmp[j] = f2bf(in_proj_w[(size_t)(c0 + j) * C_DIM + col]);
                bfr[nt] = *(const short8*)tmp;
            } else {
                const float* wp = out_w + (size_t)col * C_DIM + c0;
                bfr[nt] = f8bf(*(const float4*)wp, *(const float4*)(wp + 4));
            }
        }
#pragma unroll
        for (int mt = 0; mt < 2; ++mt)
#pragma unroll
            for (int nt = 0; nt < 2; ++nt)
                acc2[mt][nt] = __builtin_amdgcn_mfma_f32_16x16x32_bf16(
                    afr[mt], bfr[nt], acc2[mt][nt], 0, 0, 0);
    }

#pragma unroll
    for (int nt = 0; nt < 2; ++nt) {
        const int col = cb2 + nt * 16 + r16;
#pragma unroll
        for (int mt = 0; mt < 2; ++mt)
#pragma unroll
            for (int r = 0; r < 4; ++r) {
                int row = m0 + mt * 16 + quad * 4 + r;
                GU[(size_t)row * GUSTR + ucol + col] = f2bf(acc2[mt][nt][r]);
            }
    }
}

// ---------------------------------------------------------------------------
// gather: out = f + mask * (softmax((G[m].f + g0)/16) @ U[m] + out_b)
//   16 lanes/pixel, 16 pixels/block, 2048 blocks. No LDS, no barriers.
//   (byte-identical to round 3 — isolating the prep fusion this round)
// ---------------------------------------------------------------------------
__global__ __launch_bounds__(256) void gather_kernel(
    const float* __restrict__ features, const int* __restrict__ inst,
    const float* __restrict__ out_b,
    const unsigned short* __restrict__ GU, const float* __restrict__ g0,
    float* __restrict__ out)
{
    const int t = threadIdx.x;
    const int p = t >> 4, s = t & 15;          // 16 lanes per pixel
    const int n = blockIdx.x * 16 + p;
    const int lab = inst[n];
    const int m = max(lab - 1, 0);
    const unsigned short* GUp = GU + (size_t)m * (L_ANCH * GUSTR) + s * 16;

    // f slice: 16 fp32 (channels s*16 .. s*16+16)
    float fr[16];
    const float4* fp = (const float4*)(features + (size_t)n * C_DIM + s * 16);
#pragma unroll
    for (int i = 0; i < 4; ++i) *(float4*)&fr[i * 4] = fp[i];

    float sc[L_ANCH];
#pragma unroll
    for (int l = 0; l < L_ANCH; ++l) {
        const uint4* rp = (const uint4*)(GUp + (size_t)l * GUSTR);
        uint4 w0 = rp[0], w1 = rp[1];          // 16 bf16 of G row
        float a = 0.f, lo, hi;
        bfx2(w0.x, lo, hi); a += lo * fr[0]  + hi * fr[1];
        bfx2(w0.y, lo, hi); a += lo * fr[2]  + hi * fr[3];
        bfx2(w0.z, lo, hi); a += lo * fr[4]  + hi * fr[5];
        bfx2(w0.w, lo, hi); a += lo * fr[6]  + hi * fr[7];
        bfx2(w1.x, lo, hi); a += lo * fr[8]  + hi * fr[9];
        bfx2(w1.y, lo, hi); a += lo * fr[10] + hi * fr[11];
        bfx2(w1.z, lo, hi); a += lo * fr[12] + hi * fr[13];
        bfx2(w1.w, lo, hi); a += lo * fr[14] + hi * fr[15];
        sc[l] = a;
    }

    const float4 g0a = *(const float4*)&g0[m * L_ANCH];
    const float4 g0b = *(const float4*)&g0[m * L_ANCH + 4];
    const float gb[L_ANCH] = {g0a.x, g0a.y, g0a.z, g0a.w, g0b.x, g0b.y, g0b.z, g0b.w};

    // butterfly reduce within each 16-lane pixel group; all lanes get sums
    float mx = -1e30f;
#pragma unroll
    for (int l = 0; l < L_ANCH; ++l) {
        float v = sc[l];
        v += __shfl_xor(v, 1);
        v += __shfl_xor(v, 2);
        v += __shfl_xor(v, 4);
        v += __shfl_xor(v, 8);
        v = (v + gb[l]) * 0.0625f;             // 1/sqrt(256)
        sc[l] = v;
        mx = fmaxf(mx, v);
    }
    float sum = 0.f;
#pragma unroll
    for (int l = 0; l < L_ANCH; ++l) { sc[l] = __expf(sc[l] - mx); sum += sc[l]; }
    const float inv = 1.f / sum;

    float y[16];
#pragma unroll
    for (int c = 0; c < 16; ++c) y[c] = 0.f;
#pragma unroll
    for (int l = 0; l < L_ANCH; ++l) {
        const float av = sc[l] * inv;
        const uint4* up = (const uint4*)(GUp + (size_t)l * GUSTR + 256);
        uint4 u0 = up[0], u1 = up[1];          // 16 bf16 of U row
        float lo, hi;
        bfx2(u0.x, lo, hi); y[0]  += av * lo; y[1]  += av * hi;
        bfx2(u0.y, lo, hi); y[2]  += av * lo; y[3]  += av * hi;
        bfx2(u0.z, lo, hi); y[4]  += av * lo; y[5]  += av * hi;
        bfx2(u0.w, lo, hi); y[6]  += av * lo; y[7]  += av * hi;
        bfx2(u1.x, lo, hi); y[8]  += av * lo; y[9]  += av * hi;
        bfx2(u1.y, lo, hi); y[10] += av * lo; y[11] += av * hi;
        bfx2(u1.z, lo, hi); y[12] += av * lo; y[13] += av * hi;
        bfx2(u1.w, lo, hi); y[14] += av * lo; y[15] += av * hi;
    }

    const float fm = (lab > 0) ? 1.f : 0.f;
    float4* op = (float4*)(out + (size_t)n * C_DIM + s * 16);
    const float4* obp = (const float4*)(out_b + s * 16);
#pragma unroll
    for (int i = 0; i < 4; ++i) {
        float4 ob = obp[i];
        float4 o;
        o.x = fr[i * 4 + 0] + fm * (y[i * 4 + 0] + ob.x);
        o.y = fr[i * 4 + 1] + fm * (y[i * 4 + 1] + ob.y);
        o.z = fr[i * 4 + 2] + fm * (y[i * 4 + 2] + ob.z);
        o.w = fr[i * 4 + 3] + fm * (y[i * 4 + 3] + ob.w);
        op[i] = o;
    }
}

// ---------------------------------------------------------------------------
extern "C" void kernel_launch(void* const* d_in, const int* in_sizes, int n_in,
                              void* d_out, int out_size, void* d_ws, size_t ws_size,
                              hipStream_t stream) {
    const float* anchors   = (const float*)d_in[0];
    const float* features  = (const float*)d_in[1];
    const int*   inst      = (const int*)d_in[2];
    const float* in_proj_w = (const float*)d_in[3];
    const float* in_proj_b = (const float*)d_in[4];
    const float* out_w     = (const float*)d_in[5];
    const float* out_b     = (const float*)d_in[6];
    float* out = (float*)d_out;

    unsigned short* GU = (unsigned short*)d_ws;               // 512*512 interleaved G|U
    float*          g0 = (float*)(GU + M_INST * L_ANCH * GUSTR); // 512 fp32

    prep_kernel<<<64, 256, 0, stream>>>(anchors, in_proj_w, in_proj_b, out_w, GU, g0);
    gather_kernel<<<NPIX / 16, 256, 0, stream>>>(features, inst, out_b, GU, g0, out);
}

// Round 5
// 123.632 us; speedup vs baseline: 1.0861x; 1.0861x over previous
//
#include <hip/hip_runtime.h>
#include <stdint.h>

#define C_DIM   256
#define L_ANCH  8
#define M_INST  64
#define NPIX    32768
#define LDSTR   264      // A-tile row stride (shorts)
#define WSTR    40       // prep W-tile row stride (shorts)
#define TSTR    80       // transpose tile row stride (shorts)

typedef __attribute__((ext_vector_type(8))) short  short8;   // 8 x bf16
typedef __attribute__((ext_vector_type(4))) float  float4v;  // MFMA C/D

__device__ __forceinline__ float bf2f(unsigned short b) {
    union { unsigned u; float f; } x; x.u = ((unsigned)b) << 16; return x.f;
}
__device__ __forceinline__ unsigned short f2bf(float f) {
    union { unsigned u; float f; } x; x.f = f;
    unsigned u = x.u;
    return (unsigned short)((u + 0x7FFFu + ((u >> 16) & 1u)) >> 16);  // RNE
}
__device__ __forceinline__ ushort4 f4bf(float4 f) {
    ushort4 v; v.x = f2bf(f.x); v.y = f2bf(f.y); v.z = f2bf(f.z); v.w = f2bf(f.w);
    return v;
}
// unpack 2 bf16 packed in a dword: 1 VALU op per element
__device__ __forceinline__ void bfx2(unsigned u, float& lo, float& hi) {
    union { unsigned u; float f; } a, b;
    a.u = u << 16; b.u = u & 0xffff0000u;
    lo = a.f; hi = b.f;
}

// ---------------------------------------------------------------------------
// P1: blocks 0..63    : K/V = anchors @ {Wk,Wv}^T + b via MFMA
//                       (b>>5 = mat, (b>>1)&15 = 32-row tile, b&1 = col half)
//     blocks 64..127  : convert out_w -> Owb (bf16)
//     blocks 128..143 : Wq -> WqT (bf16 TRANSPOSED) via LDS 64x64 tile
// (round-0 proven structure — prep restructures in r1-r4 all regressed)
// ---------------------------------------------------------------------------
__global__ __launch_bounds__(256) void prep1_kernel(
    const float* __restrict__ anchors, const float* __restrict__ in_proj_w,
    const float* __restrict__ in_proj_b, const float* __restrict__ out_w,
    unsigned short* __restrict__ Kb, unsigned short* __restrict__ Vb,
    unsigned short* __restrict__ WqT, unsigned short* __restrict__ Owb)
{
    __shared__ unsigned short Abuf[32 * LDSTR];
    __shared__ unsigned short Wtile[4][32 * WSTR];
    __shared__ unsigned short Ttile[64 * TSTR];
    const int b = blockIdx.x, t = threadIdx.x;

    if (b >= 128) {          // ---- WqT transpose: 16 blocks, 64x64 tiles ----
        const int tidx = b - 128;
        const int r0 = (tidx >> 2) * 64, c0 = (tidx & 3) * 64;
#pragma unroll
        for (int i = 0; i < 4; ++i) {
            int id = t + i * 256;            // 1024 float4 chunks
            int row = id >> 4, c4 = id & 15;
            float4 f = *(const float4*)&in_proj_w[(size_t)(r0 + row) * C_DIM + c0 + c4 * 4];
            Ttile[(c4 * 4 + 0) * TSTR + row] = f2bf(f.x);
            Ttile[(c4 * 4 + 1) * TSTR + row] = f2bf(f.y);
            Ttile[(c4 * 4 + 2) * TSTR + row] = f2bf(f.z);
            Ttile[(c4 * 4 + 3) * TSTR + row] = f2bf(f.w);
        }
        __syncthreads();
#pragma unroll
        for (int i = 0; i < 2; ++i) {
            int id = t + i * 256;            // 512 short8 chunks
            int cc = id >> 3, ch = id & 7;
            *(short8*)&WqT[(size_t)(c0 + cc) * C_DIM + r0 + ch * 8] =
                *(const short8*)&Ttile[cc * TSTR + ch * 8];
        }
        return;
    }

    if (b >= 64) {           // ---- Owb convert: 64 blocks ----
        const int id = (b - 64) * 256 + t;   // 16384 float4 chunks
        float4 f = *((const float4*)out_w + id);
        *((ushort4*)Owb + id) = f4bf(f);
        return;
    }

    // ---- K/V MFMA GEMM: 64 blocks (mat x 16 tiles x 2 col-halves) ----
    const int mat = b >> 5, tile = (b >> 1) & 15, half = b & 1;
    const int m0 = tile * 32;
#pragma unroll
    for (int i = 0; i < 8; ++i) {
        int id = t + i * 256;
        int row = id >> 6, c4 = id & 63;
        float4 f = *((const float4*)(anchors + (size_t)(m0 + row) * C_DIM) + c4);
        *(ushort4*)&Abuf[row * LDSTR + c4 * 4] = f4bf(f);
    }
    __syncthreads();

    const int wave = t >> 6, lane = t & 63, r16 = lane & 15, quad = lane >> 4;
    const int colbase = half * 128 + wave * 32;                 // 32 cols per wave
    const int wbase = C_DIM + mat * C_DIM + colbase;            // W row range
    unsigned short* Wl = &Wtile[wave][0];                       // 32 x WSTR

    float4v acc[2][2];
#pragma unroll
    for (int mt = 0; mt < 2; ++mt)
#pragma unroll
        for (int nt = 0; nt < 2; ++nt)
#pragma unroll
            for (int r = 0; r < 4; ++r) acc[mt][nt][r] = 0.f;

    for (int ks = 0; ks < 8; ++ks) {
        const int rr = lane >> 3, cc = lane & 7;
#pragma unroll
        for (int i = 0; i < 4; ++i) {
            int row = rr + i * 8;           // 32 W rows
            float4 f = *((const float4*)(in_proj_w + (size_t)(wbase + row) * C_DIM + ks * 32) + cc);
            *(ushort4*)&Wl[row * WSTR + cc * 4] = f4bf(f);
        }
        const int c0 = ks * 32 + quad * 8;
        short8 afr[2], bfr[2];
#pragma unroll
        for (int mt = 0; mt < 2; ++mt)
            afr[mt] = *(const short8*)&Abuf[(mt * 16 + r16) * LDSTR + c0];
#pragma unroll
        for (int nt = 0; nt < 2; ++nt)
            bfr[nt] = *(const short8*)&Wl[(nt * 16 + r16) * WSTR + quad * 8];
#pragma unroll
        for (int mt = 0; mt < 2; ++mt)
#pragma unroll
            for (int nt = 0; nt < 2; ++nt)
                acc[mt][nt] = __builtin_amdgcn_mfma_f32_16x16x32_bf16(
                    afr[mt], bfr[nt], acc[mt][nt], 0, 0, 0);
    }

    unsigned short* dst = mat ? Vb : Kb;
#pragma unroll
    for (int nt = 0; nt < 2; ++nt) {
        const int col = colbase + nt * 16 + r16;
        const float bias = in_proj_b[C_DIM + mat * C_DIM + col];
#pragma unroll
        for (int mt = 0; mt < 2; ++mt)
#pragma unroll
            for (int r = 0; r < 4; ++r) {
                int row = m0 + mt * 16 + quad * 4 + r;
                dst[(size_t)row * C_DIM + col] = f2bf(acc[mt][nt][r] + bias);
            }
    }
}

// ---------------------------------------------------------------------------
// P2: blocks 0..31 : G = K @ WqT^T + (g0 = K.bq on half==0)
//     blocks 32..63: U = V @ Owb^T
//   (b>>1)&15 = 32-row tile, b&1 = col half; round-0 proven pattern
// ---------------------------------------------------------------------------
__global__ __launch_bounds__(256) void prep2_kernel(
    const unsigned short* __restrict__ Kb, const unsigned short* __restrict__ Vb,
    const unsigned short* __restrict__ WqT, const unsigned short* __restrict__ Owb,
    const float* __restrict__ in_proj_b,
    unsigned short* __restrict__ G, unsigned short* __restrict__ U,
    float* __restrict__ g0)
{
    __shared__ unsigned short Abuf[32 * LDSTR];
    const int b = blockIdx.x, t = threadIdx.x;
    const int isG = (b < 32) ? 1 : 0;
    const int tile = (b >> 1) & 15, half = b & 1;
    const int m0 = tile * 32;
    const unsigned short* src = isG ? Kb : Vb;
    const unsigned short* W   = isG ? WqT : Owb;
    unsigned short* dst       = isG ? G : U;

#pragma unroll
    for (int i = 0; i < 4; ++i) {
        int id = t + i * 256;            // 1024 short8 chunks
        int row = id >> 5, c8 = id & 31;
        *(short8*)&Abuf[row * LDSTR + c8 * 8] =
            *(const short8*)&src[(size_t)(m0 + row) * C_DIM + c8 * 8];
    }
    __syncthreads();

    const int wave = t >> 6, lane = t & 63, r16 = lane & 15, quad = lane >> 4;

    if (isG && half == 0) {
        const int grow = t >> 3, gs = t & 7;
        float gp = 0.f;
#pragma unroll
        for (int c = 0; c < 32; ++c)
            gp += bf2f(Abuf[grow * LDSTR + gs * 32 + c]) * in_proj_b[gs * 32 + c];
        gp += __shfl_down(gp, 1);
        gp += __shfl_down(gp, 2);
        gp += __shfl_down(gp, 4);
        if (gs == 0) g0[m0 + grow] = gp;
    }

    const int colbase = half * 128 + wave * 32;

    float4v acc[2][2];
#pragma unroll
    for (int mt = 0; mt < 2; ++mt)
#pragma unroll
        for (int nt = 0; nt < 2; ++nt)
#pragma unroll
            for (int r = 0; r < 4; ++r) acc[mt][nt][r] = 0.f;

    for (int ks = 0; ks < 8; ++ks) {
        const int c0 = ks * 32 + quad * 8;
        short8 afr[2], bfr[2];
#pragma unroll
        for (int mt = 0; mt < 2; ++mt)
            afr[mt] = *(const short8*)&Abuf[(mt * 16 + r16) * LDSTR + c0];
#pragma unroll
        for (int nt = 0; nt < 2; ++nt)
            bfr[nt] = *(const short8*)&W[(size_t)(colbase + nt * 16 + r16) * C_DIM + c0];
#pragma unroll
        for (int mt = 0; mt < 2; ++mt)
#pragma unroll
            for (int nt = 0; nt < 2; ++nt)
                acc[mt][nt] = __builtin_amdgcn_mfma_f32_16x16x32_bf16(
                    afr[mt], bfr[nt], acc[mt][nt], 0, 0, 0);
    }

#pragma unroll
    for (int nt = 0; nt < 2; ++nt) {
        const int col = colbase + nt * 16 + r16;
#pragma unroll
        for (int mt = 0; mt < 2; ++mt)
#pragma unroll
            for (int r = 0; r < 4; ++r) {
                int row = m0 + mt * 16 + quad * 4 + r;
                dst[(size_t)row * C_DIM + col] = f2bf(acc[mt][nt][r]);
            }
    }
}

// ---------------------------------------------------------------------------
// gather: out = f + mask * (softmax((G[m].f + g0)/16) @ U[m] + out_b)
//   16 lanes/pixel, 16 pixels/block, 2048 blocks. No LDS, no barriers.
//   Only change vs round-0 gather: uint4+bfx2 unpack (1 VALU/elem instead
//   of 2) and butterfly softmax (32 shuffles vs 40, no divergent branch,
//   no broadcast pass). No prefetch arrays; no waves/EU clamp.
// ---------------------------------------------------------------------------
__global__ __launch_bounds__(256) void gather_kernel(
    const float* __restrict__ features, const int* __restrict__ inst,
    const float* __restrict__ out_b,
    const unsigned short* __restrict__ G, const unsigned short* __restrict__ U,
    const float* __restrict__ g0, float* __restrict__ out)
{
    const int t = threadIdx.x;
    const int p = t >> 4, s = t & 15;          // 16 lanes per pixel
    const int n = blockIdx.x * 16 + p;
    const int lab = inst[n];
    const int m = max(lab - 1, 0);
    const unsigned short* Gp = G + (size_t)m * (L_ANCH * C_DIM) + s * 16;
    const unsigned short* Up = U + (size_t)m * (L_ANCH * C_DIM) + s * 16;

    // f slice: 16 fp32 (channels s*16 .. s*16+16)
    float fr[16];
    const float4* fp = (const float4*)(features + (size_t)n * C_DIM + s * 16);
#pragma unroll
    for (int i = 0; i < 4; ++i) *(float4*)&fr[i * 4] = fp[i];

    float sc[L_ANCH];
#pragma unroll
    for (int l = 0; l < L_ANCH; ++l) {
        const uint4* rp = (const uint4*)(Gp + (size_t)l * C_DIM);
        uint4 w0 = rp[0], w1 = rp[1];          // 16 bf16 of G row
        float a = 0.f, lo, hi;
        bfx2(w0.x, lo, hi); a += lo * fr[0]  + hi * fr[1];
        bfx2(w0.y, lo, hi); a += lo * fr[2]  + hi * fr[3];
        bfx2(w0.z, lo, hi); a += lo * fr[4]  + hi * fr[5];
        bfx2(w0.w, lo, hi); a += lo * fr[6]  + hi * fr[7];
        bfx2(w1.x, lo, hi); a += lo * fr[8]  + hi * fr[9];
        bfx2(w1.y, lo, hi); a += lo * fr[10] + hi * fr[11];
        bfx2(w1.z, lo, hi); a += lo * fr[12] + hi * fr[13];
        bfx2(w1.w, lo, hi); a += lo * fr[14] + hi * fr[15];
        sc[l] = a;
    }

    const float4 g0a = *(const float4*)&g0[m * L_ANCH];
    const float4 g0b = *(const float4*)&g0[m * L_ANCH + 4];
    const float gb[L_ANCH] = {g0a.x, g0a.y, g0a.z, g0a.w, g0b.x, g0b.y, g0b.z, g0b.w};

    // butterfly reduce within each 16-lane pixel group; all lanes get sums
    float mx = -1e30f;
#pragma unroll
    for (int l = 0; l < L_ANCH; ++l) {
        float v = sc[l];
        v += __shfl_xor(v, 1);
        v += __shfl_xor(v, 2);
        v += __shfl_xor(v, 4);
        v += __shfl_xor(v, 8);
        v = (v + gb[l]) * 0.0625f;             // 1/sqrt(256)
        sc[l] = v;
        mx = fmaxf(mx, v);
    }
    float sum = 0.f;
#pragma unroll
    for (int l = 0; l < L_ANCH; ++l) { sc[l] = __expf(sc[l] - mx); sum += sc[l]; }
    const float inv = 1.f / sum;

    float y[16];
#pragma unroll
    for (int c = 0; c < 16; ++c) y[c] = 0.f;
#pragma unroll
    for (int l = 0; l < L_ANCH; ++l) {
        const float av = sc[l] * inv;
        const uint4* up = (const uint4*)(Up + (size_t)l * C_DIM);
        uint4 u0 = up[0], u1 = up[1];          // 16 bf16 of U row
        float lo, hi;
        bfx2(u0.x, lo, hi); y[0]  += av * lo; y[1]  += av * hi;
        bfx2(u0.y, lo, hi); y[2]  += av * lo; y[3]  += av * hi;
        bfx2(u0.z, lo, hi); y[4]  += av * lo; y[5]  += av * hi;
        bfx2(u0.w, lo, hi); y[6]  += av * lo; y[7]  += av * hi;
        bfx2(u1.x, lo, hi); y[8]  += av * lo; y[9]  += av * hi;
        bfx2(u1.y, lo, hi); y[10] += av * lo; y[11] += av * hi;
        bfx2(u1.z, lo, hi); y[12] += av * lo; y[13] += av * hi;
        bfx2(u1.w, lo, hi); y[14] += av * lo; y[15] += av * hi;
    }

    const float fm = (lab > 0) ? 1.f : 0.f;
    float4* op = (float4*)(out + (size_t)n * C_DIM + s * 16);
    const float4* obp = (const float4*)(out_b + s * 16);
#pragma unroll
    for (int i = 0; i < 4; ++i) {
        float4 ob = obp[i];
        float4 o;
        o.x = fr[i * 4 + 0] + fm * (y[i * 4 + 0] + ob.x);
        o.y = fr[i * 4 + 1] + fm * (y[i * 4 + 1] + ob.y);
        o.z = fr[i * 4 + 2] + fm * (y[i * 4 + 2] + ob.z);
        o.w = fr[i * 4 + 3] + fm * (y[i * 4 + 3] + ob.w);
        op[i] = o;
    }
}

// ---------------------------------------------------------------------------
extern "C" void kernel_launch(void* const* d_in, const int* in_sizes, int n_in,
                              void* d_out, int out_size, void* d_ws, size_t ws_size,
                              hipStream_t stream) {
    const float* anchors   = (const float*)d_in[0];
    const float* features  = (const float*)d_in[1];
    const int*   inst      = (const int*)d_in[2];
    const float* in_proj_w = (const float*)d_in[3];
    const float* in_proj_b = (const float*)d_in[4];
    const float* out_w     = (const float*)d_in[5];
    const float* out_b     = (const float*)d_in[6];
    float* out = (float*)d_out;

    unsigned short* Kb  = (unsigned short*)d_ws;              // 512*256 bf16
    unsigned short* Vb  = Kb  + M_INST * L_ANCH * C_DIM;      // 512*256
    unsigned short* WqT = Vb  + M_INST * L_ANCH * C_DIM;      // 256*256 (transposed)
    unsigned short* Owb = WqT + C_DIM * C_DIM;                // 256*256
    unsigned short* G   = Owb + C_DIM * C_DIM;                // 512*256
    unsigned short* U   = G   + M_INST * L_ANCH * C_DIM;      // 512*256
    float*          g0  = (float*)(U + M_INST * L_ANCH * C_DIM); // 512 fp32

    prep1_kernel<<<144, 256, 0, stream>>>(anchors, in_proj_w, in_proj_b, out_w,
                                          Kb, Vb, WqT, Owb);
    prep2_kernel<<<64, 256, 0, stream>>>(Kb, Vb, WqT, Owb, in_proj_b, G, U, g0);
    gather_kernel<<<NPIX / 16, 256, 0, stream>>>(features, inst, out_b, G, U, g0, out);
}

// Round 6
// 115.695 us; speedup vs baseline: 1.1606x; 1.0686x over previous
//
#include <hip/hip_runtime.h>
#include <stdint.h>

#define C_DIM   256
#define L_ANCH  8
#define M_INST  64
#define NPIX    32768
#define LDSTR   264      // A-tile row stride (shorts)
#define WSTR    40       // prep W-tile row stride (shorts)
#define TSTR    80       // transpose tile row stride (shorts)

typedef __attribute__((ext_vector_type(8))) short  short8;   // 8 x bf16
typedef __attribute__((ext_vector_type(4))) float  float4v;  // MFMA C/D

__device__ __forceinline__ float bf2f(unsigned short b) {
    union { unsigned u; float f; } x; x.u = ((unsigned)b) << 16; return x.f;
}
__device__ __forceinline__ unsigned short f2bf(float f) {
    union { unsigned u; float f; } x; x.f = f;
    unsigned u = x.u;
    return (unsigned short)((u + 0x7FFFu + ((u >> 16) & 1u)) >> 16);  // RNE
}
__device__ __forceinline__ ushort4 f4bf(float4 f) {
    ushort4 v; v.x = f2bf(f.x); v.y = f2bf(f.y); v.z = f2bf(f.z); v.w = f2bf(f.w);
    return v;
}
// unpack 2 bf16 packed in a dword: 1 VALU op per element
__device__ __forceinline__ void bfx2(unsigned u, float& lo, float& hi) {
    union { unsigned u; float f; } a, b;
    a.u = u << 16; b.u = u & 0xffff0000u;
    lo = a.f; hi = b.f;
}

// ---------------------------------------------------------------------------
// P1: blocks 0..63    : K/V = anchors @ {Wk,Wv}^T + b via MFMA
//                       (b>>5 = mat, (b>>1)&15 = 32-row tile, b&1 = col half)
//     blocks 64..127  : convert out_w -> Owb (bf16)
//     blocks 128..143 : Wq -> WqT (bf16 TRANSPOSED) via LDS 64x64 tile
// (round-0 proven structure — prep restructures in r1-r4 all regressed)
// ---------------------------------------------------------------------------
__global__ __launch_bounds__(256) void prep1_kernel(
    const float* __restrict__ anchors, const float* __restrict__ in_proj_w,
    const float* __restrict__ in_proj_b, const float* __restrict__ out_w,
    unsigned short* __restrict__ Kb, unsigned short* __restrict__ Vb,
    unsigned short* __restrict__ WqT, unsigned short* __restrict__ Owb)
{
    __shared__ unsigned short Abuf[32 * LDSTR];
    __shared__ unsigned short Wtile[4][32 * WSTR];
    __shared__ unsigned short Ttile[64 * TSTR];
    const int b = blockIdx.x, t = threadIdx.x;

    if (b >= 128) {          // ---- WqT transpose: 16 blocks, 64x64 tiles ----
        const int tidx = b - 128;
        const int r0 = (tidx >> 2) * 64, c0 = (tidx & 3) * 64;
#pragma unroll
        for (int i = 0; i < 4; ++i) {
            int id = t + i * 256;            // 1024 float4 chunks
            int row = id >> 4, c4 = id & 15;
            float4 f = *(const float4*)&in_proj_w[(size_t)(r0 + row) * C_DIM + c0 + c4 * 4];
            Ttile[(c4 * 4 + 0) * TSTR + row] = f2bf(f.x);
            Ttile[(c4 * 4 + 1) * TSTR + row] = f2bf(f.y);
            Ttile[(c4 * 4 + 2) * TSTR + row] = f2bf(f.z);
            Ttile[(c4 * 4 + 3) * TSTR + row] = f2bf(f.w);
        }
        __syncthreads();
#pragma unroll
        for (int i = 0; i < 2; ++i) {
            int id = t + i * 256;            // 512 short8 chunks
            int cc = id >> 3, ch = id & 7;
            *(short8*)&WqT[(size_t)(c0 + cc) * C_DIM + r0 + ch * 8] =
                *(const short8*)&Ttile[cc * TSTR + ch * 8];
        }
        return;
    }

    if (b >= 64) {           // ---- Owb convert: 64 blocks ----
        const int id = (b - 64) * 256 + t;   // 16384 float4 chunks
        float4 f = *((const float4*)out_w + id);
        *((ushort4*)Owb + id) = f4bf(f);
        return;
    }

    // ---- K/V MFMA GEMM: 64 blocks (mat x 16 tiles x 2 col-halves) ----
    const int mat = b >> 5, tile = (b >> 1) & 15, half = b & 1;
    const int m0 = tile * 32;
#pragma unroll
    for (int i = 0; i < 8; ++i) {
        int id = t + i * 256;
        int row = id >> 6, c4 = id & 63;
        float4 f = *((const float4*)(anchors + (size_t)(m0 + row) * C_DIM) + c4);
        *(ushort4*)&Abuf[row * LDSTR + c4 * 4] = f4bf(f);
    }
    __syncthreads();

    const int wave = t >> 6, lane = t & 63, r16 = lane & 15, quad = lane >> 4;
    const int colbase = half * 128 + wave * 32;                 // 32 cols per wave
    const int wbase = C_DIM + mat * C_DIM + colbase;            // W row range
    unsigned short* Wl = &Wtile[wave][0];                       // 32 x WSTR

    float4v acc[2][2];
#pragma unroll
    for (int mt = 0; mt < 2; ++mt)
#pragma unroll
        for (int nt = 0; nt < 2; ++nt)
#pragma unroll
            for (int r = 0; r < 4; ++r) acc[mt][nt][r] = 0.f;

    for (int ks = 0; ks < 8; ++ks) {
        const int rr = lane >> 3, cc = lane & 7;
#pragma unroll
        for (int i = 0; i < 4; ++i) {
            int row = rr + i * 8;           // 32 W rows
            float4 f = *((const float4*)(in_proj_w + (size_t)(wbase + row) * C_DIM + ks * 32) + cc);
            *(ushort4*)&Wl[row * WSTR + cc * 4] = f4bf(f);
        }
        const int c0 = ks * 32 + quad * 8;
        short8 afr[2], bfr[2];
#pragma unroll
        for (int mt = 0; mt < 2; ++mt)
            afr[mt] = *(const short8*)&Abuf[(mt * 16 + r16) * LDSTR + c0];
#pragma unroll
        for (int nt = 0; nt < 2; ++nt)
            bfr[nt] = *(const short8*)&Wl[(nt * 16 + r16) * WSTR + quad * 8];
#pragma unroll
        for (int mt = 0; mt < 2; ++mt)
#pragma unroll
            for (int nt = 0; nt < 2; ++nt)
                acc[mt][nt] = __builtin_amdgcn_mfma_f32_16x16x32_bf16(
                    afr[mt], bfr[nt], acc[mt][nt], 0, 0, 0);
    }

    unsigned short* dst = mat ? Vb : Kb;
#pragma unroll
    for (int nt = 0; nt < 2; ++nt) {
        const int col = colbase + nt * 16 + r16;
        const float bias = in_proj_b[C_DIM + mat * C_DIM + col];
#pragma unroll
        for (int mt = 0; mt < 2; ++mt)
#pragma unroll
            for (int r = 0; r < 4; ++r) {
                int row = m0 + mt * 16 + quad * 4 + r;
                dst[(size_t)row * C_DIM + col] = f2bf(acc[mt][nt][r] + bias);
            }
    }
}

// ---------------------------------------------------------------------------
// P2: blocks 0..31 : G = K @ WqT^T + (g0 = K.bq on half==0)
//     blocks 32..63: U = V @ Owb^T
//   (b>>1)&15 = 32-row tile, b&1 = col half; round-0 proven pattern
// ---------------------------------------------------------------------------
__global__ __launch_bounds__(256) void prep2_kernel(
    const unsigned short* __restrict__ Kb, const unsigned short* __restrict__ Vb,
    const unsigned short* __restrict__ WqT, const unsigned short* __restrict__ Owb,
    const float* __restrict__ in_proj_b,
    unsigned short* __restrict__ G, unsigned short* __restrict__ U,
    float* __restrict__ g0)
{
    __shared__ unsigned short Abuf[32 * LDSTR];
    const int b = blockIdx.x, t = threadIdx.x;
    const int isG = (b < 32) ? 1 : 0;
    const int tile = (b >> 1) & 15, half = b & 1;
    const int m0 = tile * 32;
    const unsigned short* src = isG ? Kb : Vb;
    const unsigned short* W   = isG ? WqT : Owb;
    unsigned short* dst       = isG ? G : U;

#pragma unroll
    for (int i = 0; i < 4; ++i) {
        int id = t + i * 256;            // 1024 short8 chunks
        int row = id >> 5, c8 = id & 31;
        *(short8*)&Abuf[row * LDSTR + c8 * 8] =
            *(const short8*)&src[(size_t)(m0 + row) * C_DIM + c8 * 8];
    }
    __syncthreads();

    const int wave = t >> 6, lane = t & 63, r16 = lane & 15, quad = lane >> 4;

    if (isG && half == 0) {
        const int grow = t >> 3, gs = t & 7;
        float gp = 0.f;
#pragma unroll
        for (int c = 0; c < 32; ++c)
            gp += bf2f(Abuf[grow * LDSTR + gs * 32 + c]) * in_proj_b[gs * 32 + c];
        gp += __shfl_down(gp, 1);
        gp += __shfl_down(gp, 2);
        gp += __shfl_down(gp, 4);
        if (gs == 0) g0[m0 + grow] = gp;
    }

    const int colbase = half * 128 + wave * 32;

    float4v acc[2][2];
#pragma unroll
    for (int mt = 0; mt < 2; ++mt)
#pragma unroll
        for (int nt = 0; nt < 2; ++nt)
#pragma unroll
            for (int r = 0; r < 4; ++r) acc[mt][nt][r] = 0.f;

    for (int ks = 0; ks < 8; ++ks) {
        const int c0 = ks * 32 + quad * 8;
        short8 afr[2], bfr[2];
#pragma unroll
        for (int mt = 0; mt < 2; ++mt)
            afr[mt] = *(const short8*)&Abuf[(mt * 16 + r16) * LDSTR + c0];
#pragma unroll
        for (int nt = 0; nt < 2; ++nt)
            bfr[nt] = *(const short8*)&W[(size_t)(colbase + nt * 16 + r16) * C_DIM + c0];
#pragma unroll
        for (int mt = 0; mt < 2; ++mt)
#pragma unroll
            for (int nt = 0; nt < 2; ++nt)
                acc[mt][nt] = __builtin_amdgcn_mfma_f32_16x16x32_bf16(
                    afr[mt], bfr[nt], acc[mt][nt], 0, 0, 0);
    }

#pragma unroll
    for (int nt = 0; nt < 2; ++nt) {
        const int col = colbase + nt * 16 + r16;
#pragma unroll
        for (int mt = 0; mt < 2; ++mt)
#pragma unroll
            for (int r = 0; r < 4; ++r) {
                int row = m0 + mt * 16 + quad * 4 + r;
                dst[(size_t)row * C_DIM + col] = f2bf(acc[mt][nt][r]);
            }
    }
}

// ---------------------------------------------------------------------------
// gather: out = f + mask * (softmax((G[m].f + g0)/16) @ U[m] + out_b)
//   NEW: 32 lanes/pixel (8 channels/lane), 8 pixels/block, 4096 blocks.
//   Rationale: halves per-lane live state (fr[8]/y[8] vs fr[16]/y[16],
//   ~56-64 VGPR -> 8 waves/SIMD vs 4-5), halves each dependent chain, and
//   doubles wave count for latency hiding. Each G/U row slice is ONE uint4
//   load per lane. Butterfly is 5 stages (xor 1,2,4,8,16 — stays within the
//   32-lane pixel group). No occupancy clamp (round-1 spill lesson).
// ---------------------------------------------------------------------------
__global__ __launch_bounds__(256) void gather_kernel(
    const float* __restrict__ features, const int* __restrict__ inst,
    const float* __restrict__ out_b,
    const unsigned short* __restrict__ G, const unsigned short* __restrict__ U,
    const float* __restrict__ g0, float* __restrict__ out)
{
    const int t = threadIdx.x;
    const int p = t >> 5, s = t & 31;          // 32 lanes per pixel
    const int n = blockIdx.x * 8 + p;
    const int lab = inst[n];
    const int m = max(lab - 1, 0);
    const unsigned short* Gp = G + (size_t)m * (L_ANCH * C_DIM) + s * 8;
    const unsigned short* Up = U + (size_t)m * (L_ANCH * C_DIM) + s * 8;

    // f slice: 8 fp32 (channels s*8 .. s*8+8)
    float fr[8];
    const float4* fp = (const float4*)(features + (size_t)n * C_DIM + s * 8);
    *(float4*)&fr[0] = fp[0];
    *(float4*)&fr[4] = fp[1];

    float sc[L_ANCH];
#pragma unroll
    for (int l = 0; l < L_ANCH; ++l) {
        uint4 w = *(const uint4*)(Gp + (size_t)l * C_DIM);   // 8 bf16 of G row
        float lo, hi, a;
        bfx2(w.x, lo, hi); a  = lo * fr[0] + hi * fr[1];
        bfx2(w.y, lo, hi); a += lo * fr[2] + hi * fr[3];
        bfx2(w.z, lo, hi); a += lo * fr[4] + hi * fr[5];
        bfx2(w.w, lo, hi); a += lo * fr[6] + hi * fr[7];
        sc[l] = a;
    }

    const float4 g0a = *(const float4*)&g0[m * L_ANCH];
    const float4 g0b = *(const float4*)&g0[m * L_ANCH + 4];
    const float gb[L_ANCH] = {g0a.x, g0a.y, g0a.z, g0a.w, g0b.x, g0b.y, g0b.z, g0b.w};

    // butterfly reduce within each 32-lane pixel group; all lanes get sums
    float mx = -1e30f;
#pragma unroll
    for (int l = 0; l < L_ANCH; ++l) {
        float v = sc[l];
        v += __shfl_xor(v, 1);
        v += __shfl_xor(v, 2);
        v += __shfl_xor(v, 4);
        v += __shfl_xor(v, 8);
        v += __shfl_xor(v, 16);
        v = (v + gb[l]) * 0.0625f;             // 1/sqrt(256)
        sc[l] = v;
        mx = fmaxf(mx, v);
    }
    float sum = 0.f;
#pragma unroll
    for (int l = 0; l < L_ANCH; ++l) { sc[l] = __expf(sc[l] - mx); sum += sc[l]; }
    const float inv = 1.f / sum;

    float y[8];
#pragma unroll
    for (int c = 0; c < 8; ++c) y[c] = 0.f;
#pragma unroll
    for (int l = 0; l < L_ANCH; ++l) {
        const float av = sc[l] * inv;
        uint4 u = *(const uint4*)(Up + (size_t)l * C_DIM);   // 8 bf16 of U row
        float lo, hi;
        bfx2(u.x, lo, hi); y[0] += av * lo; y[1] += av * hi;
        bfx2(u.y, lo, hi); y[2] += av * lo; y[3] += av * hi;
        bfx2(u.z, lo, hi); y[4] += av * lo; y[5] += av * hi;
        bfx2(u.w, lo, hi); y[6] += av * lo; y[7] += av * hi;
    }

    const float fm = (lab > 0) ? 1.f : 0.f;
    float4* op = (float4*)(out + (size_t)n * C_DIM + s * 8);
    const float4* obp = (const float4*)(out_b + s * 8);
#pragma unroll
    for (int i = 0; i < 2; ++i) {
        float4 ob = obp[i];
        float4 o;
        o.x = fr[i * 4 + 0] + fm * (y[i * 4 + 0] + ob.x);
        o.y = fr[i * 4 + 1] + fm * (y[i * 4 + 1] + ob.y);
        o.z = fr[i * 4 + 2] + fm * (y[i * 4 + 2] + ob.z);
        o.w = fr[i * 4 + 3] + fm * (y[i * 4 + 3] + ob.w);
        op[i] = o;
    }
}

// ---------------------------------------------------------------------------
extern "C" void kernel_launch(void* const* d_in, const int* in_sizes, int n_in,
                              void* d_out, int out_size, void* d_ws, size_t ws_size,
                              hipStream_t stream) {
    const float* anchors   = (const float*)d_in[0];
    const float* features  = (const float*)d_in[1];
    const int*   inst      = (const int*)d_in[2];
    const float* in_proj_w = (const float*)d_in[3];
    const float* in_proj_b = (const float*)d_in[4];
    const float* out_w     = (const float*)d_in[5];
    const float* out_b     = (const float*)d_in[6];
    float* out = (float*)d_out;

    unsigned short* Kb  = (unsigned short*)d_ws;              // 512*256 bf16
    unsigned short* Vb  = Kb  + M_INST * L_ANCH * C_DIM;      // 512*256
    unsigned short* WqT = Vb  + M_INST * L_ANCH * C_DIM;      // 256*256 (transposed)
    unsigned short* Owb = WqT + C_DIM * C_DIM;                // 256*256
    unsigned short* G   = Owb + C_DIM * C_DIM;                // 512*256
    unsigned short* U   = G   + M_INST * L_ANCH * C_DIM;      // 512*256
    float*          g0  = (float*)(U + M_INST * L_ANCH * C_DIM); // 512 fp32

    prep1_kernel<<<144, 256, 0, stream>>>(anchors, in_proj_w, in_proj_b, out_w,
                                          Kb, Vb, WqT, Owb);
    prep2_kernel<<<64, 256, 0, stream>>>(Kb, Vb, WqT, Owb, in_proj_b, G, U, g0);
    gather_kernel<<<NPIX / 8, 256, 0, stream>>>(features, inst, out_b, G, U, g0, out);
}